// Round 13
// baseline (102.384 us; speedup 1.0000x reference)
//
#include <hip/hip_runtime.h>

// Problem constants (from reference: B=8, N=8192, M=2500, P=10)
#define B_   8
#define N_   8192
#define M_   2500
#define SPP_ 250
#define EPS_ 1e-20f
#define BIGF 1e30f

// ---- kernel-1 roles ----
// p2gt: 8 z-chunks (1024 gt) x 8 b x 5 mblk (512 preds)  = 320  (32 iters)
// gt2p: 2 z-chunks (1280 pd) x 8 b x 16 mblk (512 gts)   = 256  (40 iters)
#define NB_P2GT 320
#define NB_GT2P 256
#define NB_FFF  79
#define NB_K1   (NB_P2GT + NB_GT2P + NB_FFF)   // 655

// ---- kernel-2 roles (float4-vectorized) ----
#define NB_RG2P 64
#define NB_RP2  20
#define NB_K2   (NB_RG2P + NB_RP2)             // 84

// ---- ws layout (float indices) ----
#define WS_P2GT 0            // 8 z x 20000 clamped partial minima
#define WS_GT2P 160000       // 2 z x 65536 clamped partial minima
#define WS_F1P  291072       // 79 x 24 fff partials (non-atomic)
#define WS_RED  292968       // k2 partials: 64 g2p + 20 p2
#define WS_CNT  293052       // k2 arrival counter (uint)
#define RO_G2P 0
#define RO_P2  64
// f1p slot order
#define F_E    0
#define F_G    1
#define F_MC   2
#define F_ST   3
#define F_F2I  4
#define F_E2I  5
#define F_EI   6
#define F_G2I  7
#define F_GI   8
#define F_I    9
#define F_AB   10   // 10..17 per-batch sum sqrt(A2)

typedef __attribute__((ext_vector_type(8)))  short short8_t;
typedef __attribute__((ext_vector_type(4)))  float float4_t;
typedef __attribute__((ext_vector_type(16))) float float16_t;

__device__ __forceinline__ unsigned pack_bf2(float lo, float hi) {
    unsigned a = __float_as_uint(lo);
    unsigned b = __float_as_uint(hi);
    a = (a + 0x7FFFu + ((a >> 16) & 1u)) >> 16;
    b = (b + 0x7FFFu + ((b >> 16) & 1u)) & 0xFFFF0000u;
    return a | b;
}
__device__ __forceinline__ short bf16s(float x) {
    unsigned a = __float_as_uint(x);
    return (short)((a + 0x7FFFu + ((a >> 16) & 1u)) >> 16);
}
__device__ __forceinline__ float wave_sum64(float v) {
    #pragma unroll
    for (int o = 32; o > 0; o >>= 1) v += __shfl_down(v, o, 64);
    return v;
}
__device__ __forceinline__ float block_sum256(float v, volatile float* red4) {
    v = wave_sum64(v);
    int wid = threadIdx.x >> 6, lane = threadIdx.x & 63;
    if (lane == 0) red4[wid] = v;
    __syncthreads();
    float r = 0.f;
    if (threadIdx.x == 0) r = red4[0] + red4[1] + red4[2] + red4[3];
    __syncthreads();
    return r;
}

// ============================================================================
// Kernel 1: MFMA chamfer via 32x32x16 bf16 (1024 pairs/MFMA) + single-pass fff.
// K=5 of 16 used: A[m] = {x,y,z,1,|a|^2,0,0,0} (half-wave lane>>5==0 holds
// k=0..7; other half zero), B[n] = {-2bx,-2by,-2bz,|b|^2,1,0,0,0}
// -> D = d^2 directly with C=0. 4 A-tiles (128 rows) per wave; one
// ds_read_b128 B-fragment (32 cols) feeds 4 MFMAs = 4096 pairs/iter.
// C/D: col=lane&31, row=(reg&3)+8*(reg>>2)+4*(lane>>5) [guide-verified].
// ============================================================================
__global__ void __launch_bounds__(256, 2) k1_main(
        const float* __restrict__ gt, const float* __restrict__ pred,
        const float* __restrict__ fff, float* __restrict__ ws) {
    __shared__ uint4 spts[1280];                 // staged B pts, 16 B each
    __shared__ __align__(16) float saux[8];      // fff red4 + sA reuse
    __shared__ float sA[B_];
    const int bid = blockIdx.x;
    const int tid = threadIdx.x;
    const int lane = tid & 63;
    const int w    = tid >> 6;
    const int l31  = lane & 31;
    const int half = lane >> 5;

    if (bid == 0 && tid == 0) ((unsigned*)(ws + WS_CNT))[0] = 0u;

    if (bid < NB_P2GT + NB_GT2P) {
        // ------------------- chamfer role -------------------
        const bool is_p2gt = bid < NB_P2GT;
        int b, mblk, z, ntiles, blim, alim;
        const float* apts; const float* bpts; float* dst;
        if (is_p2gt) {
            z = bid / 40; int rem = bid % 40;
            b = rem / 5;  mblk = rem % 5;
            apts = pred + (size_t)b * M_ * 3;
            bpts = gt + ((size_t)b * N_ + (size_t)z * 1024) * 3;
            ntiles = 32; blim = 1024; alim = M_;
            dst = ws + WS_P2GT + (size_t)z * 20000 + b * M_;
        } else {
            int r = bid - NB_P2GT;
            z = r >> 7; int rem = r & 127;
            b = rem >> 4; mblk = rem & 15;
            apts = gt + (size_t)b * N_ * 3;
            bpts = pred + ((size_t)b * M_ + (size_t)z * 1280) * 3;
            ntiles = 40; blim = M_ - z * 1280; alim = N_;
            dst = ws + WS_GT2P + (size_t)z * 65536 + b * N_;
        }
        const int abase = mblk * 512;
        const int nstage = ntiles * 32;

        // stage B points: {-2x,-2y | -2z,n2 | 1,0 | 0,0} bf16-packed, 16 B
        for (int i = tid; i < nstage; i += 256) {
            float x = 0.f, y = 0.f, zc = 0.f, n2 = BIGF;
            if (i < blim) {
                x = bpts[i * 3 + 0]; y = bpts[i * 3 + 1]; zc = bpts[i * 3 + 2];
                n2 = x * x + y * y + zc * zc;
            }
            uint4 q;
            q.x = pack_bf2(-2.f * x, -2.f * y);
            q.y = pack_bf2(-2.f * zc, n2);
            q.z = 0x00003F80u;   // {1.0bf, 0}
            q.w = 0u;
            spts[i] = q;
        }

        // A fragments: 4 tiles of 32 rows per wave (128 rows)
        short8_t af[4];
        #pragma unroll
        for (int t = 0; t < 4; ++t) af[t] = (short8_t){0,0,0,0,0,0,0,0};
        if (half == 0) {   // k=0..7 half holds the data; other half k=8..15 -> 0
            #pragma unroll
            for (int t = 0; t < 4; ++t) {
                int m = abase + w * 128 + t * 32 + l31;
                int c = m < alim ? m : alim - 1;
                float x = apts[c*3+0], y = apts[c*3+1], zc = apts[c*3+2];
                float n2 = x*x + y*y + zc*zc;
                af[t][0] = bf16s(x); af[t][1] = bf16s(y); af[t][2] = bf16s(zc);
                af[t][3] = (short)0x3F80;   // 1.0
                af[t][4] = bf16s(n2);       // |a|^2 (bf16; error << threshold)
            }
        }
        __syncthreads();

        const float16_t z16 = (float16_t)0.f;
        float16_t c[4];
        #pragma unroll
        for (int t = 0; t < 4; ++t) c[t] = (float16_t)BIGF;

        const uint4* bptr = spts + l31;   // halves duplicate address = bcast
        #pragma unroll 2
        for (int i = 0; i < ntiles; ++i) {
            short8_t bf = __builtin_bit_cast(short8_t, bptr[i * 32]);
            #pragma unroll
            for (int t = 0; t < 4; ++t) {
                float16_t d = __builtin_amdgcn_mfma_f32_32x32x16_bf16(
                                  af[t], bf, z16, 0, 0, 0);
                #pragma unroll
                for (int r = 0; r < 16; ++r) c[t][r] = fminf(c[t][r], d[r]);
            }
        }

        // reduce over 32 cols (butterfly within each 32-lane half)
        #pragma unroll
        for (int t = 0; t < 4; ++t) {
            #pragma unroll
            for (int m = 1; m < 32; m <<= 1) {
                #pragma unroll
                for (int r = 0; r < 16; ++r)
                    c[t][r] = fminf(c[t][r], __shfl_xor(c[t][r], m, 64));
            }
        }
        // store: lane l31==0 of each half writes 4 float4 groups per tile;
        // rows = tilebase + 8*j + 4*half + {0..3}  (from regs 4j..4j+3)
        if (l31 == 0) {
            #pragma unroll
            for (int t = 0; t < 4; ++t) {
                int tb = abase + w * 128 + t * 32 + 4 * half;
                #pragma unroll
                for (int j = 0; j < 4; ++j) {
                    int m0 = tb + 8 * j;
                    if (m0 < alim) {   // alim % 4 == 0 -> no straddle
                        float4_t v;
                        v.x = fmaxf(c[t][4*j+0], 0.f);
                        v.y = fmaxf(c[t][4*j+1], 0.f);
                        v.z = fmaxf(c[t][4*j+2], 0.f);
                        v.w = fmaxf(c[t][4*j+3], 0.f);
                        *(float4_t*)(dst + m0) = v;
                    }
                }
            }
        }
    } else {
        // ------------- fff role (single pass, expanded variance) -------------
        const int kb = bid - NB_P2GT - NB_GT2P;
        const int i  = kb * 256 + tid;
        volatile float* red4 = saux;
        if (tid < B_) sA[tid] = 0.f;
        __syncthreads();

        float vE=0.f,vG=0.f,vMC=0.f,vST=0.f,vF2=0.f,vE2=0.f,vEI=0.f,
              vG2=0.f,vGI=0.f,vI=0.f;
        if (i < B_ * M_) {
            const int b = i / M_;
            const int m = i - b * M_;
            const float* f = fff + (size_t)i * 3;
            float E = f[0], F = f[1], G = f[2];
            float A2  = fmaxf(E * G - F * F, 0.f);
            float inv = 1.f / (A2 + EPS_);
            vE = E; vG = G;
            vST = (E - G) * (E - G) * inv;
            vF2 = F * F * inv;
            vE2 = E * E * inv; vEI = E * inv;
            vG2 = G * G * inv; vGI = G * inv;
            vI  = inv;
            atomicAdd(&sA[b], sqrtf(A2));
            if ((b & 1) == 0) {
                const float* f2 = fff + ((size_t)(b + 1) * M_ + m) * 3;
                float dE = E - f2[0], dF = F - f2[1], dG = G - f2[2];
                vMC = dE * dE + 2.f * dF * dF + dG * dG;
            }
        }
        float* outp = ws + WS_F1P + (size_t)kb * 24;
        float r;
        r = block_sum256(vE,  red4); if (tid==0) outp[F_E]   = r;
        r = block_sum256(vG,  red4); if (tid==0) outp[F_G]   = r;
        r = block_sum256(vMC, red4); if (tid==0) outp[F_MC]  = r;
        r = block_sum256(vST, red4); if (tid==0) outp[F_ST]  = r;
        r = block_sum256(vF2, red4); if (tid==0) outp[F_F2I] = r;
        r = block_sum256(vE2, red4); if (tid==0) outp[F_E2I] = r;
        r = block_sum256(vEI, red4); if (tid==0) outp[F_EI]  = r;
        r = block_sum256(vG2, red4); if (tid==0) outp[F_G2I] = r;
        r = block_sum256(vGI, red4); if (tid==0) outp[F_GI]  = r;
        r = block_sum256(vI,  red4); if (tid==0) outp[F_I]   = r;
        __syncthreads();
        if (tid < B_) outp[F_AB + tid] = sA[tid];
    }
}

// ============================================================================
// Kernel 2: min-over-z (float4-vectorized) + last-block finalize.
// ============================================================================
__global__ void __launch_bounds__(256) k2_reduce(
        const float* __restrict__ fff, const float* __restrict__ A_gt,
        float* __restrict__ ws, float* __restrict__ out) {
    __shared__ float red4[4];
    const int bid = blockIdx.x;
    const int tid = threadIdx.x;
    float* redp = ws + WS_RED;
    const float* f1p = ws + WS_F1P;

    if (bid < NB_RG2P) {
        const int o = bid * 1024 + tid * 4;          // [0,65536)
        const float4_t v0 = *(const float4_t*)(ws + WS_GT2P + o);
        const float4_t v1 = *(const float4_t*)(ws + WS_GT2P + 65536 + o);
        float s = fminf(v0.x, v1.x) + fminf(v0.y, v1.y)
                + fminf(v0.z, v1.z) + fminf(v0.w, v1.w);
        float r = block_sum256(s, red4);
        if (tid == 0) redp[RO_G2P + bid] = r;
    } else {
        const int kb = bid - NB_RG2P;
        const int o = kb * 1024 + tid * 4;           // [0,20480)
        float s = 0.f;
        if (o < 20000) {
            const float* src = ws + WS_P2GT + o;
            float4_t m = *(const float4_t*)src;
            #pragma unroll
            for (int zz = 1; zz < 8; ++zz) {
                float4_t v = *(const float4_t*)(src + zz * 20000);
                m.x = fminf(m.x, v.x); m.y = fminf(m.y, v.y);
                m.z = fminf(m.z, v.z); m.w = fminf(m.w, v.w);
            }
            s = m.x + m.y + m.z + m.w;
        }
        float r = block_sum256(s, red4);
        if (tid == 0) redp[RO_P2 + kb] = r;
    }

    // ---- arrival counter; last block finalizes ----
    __syncthreads();
    if (tid == 0) __threadfence();
    __syncthreads();
    __shared__ unsigned old_s;
    if (tid == 0)
        old_s = __hip_atomic_fetch_add((unsigned*)(ws + WS_CNT), 1u,
                                       __ATOMIC_ACQ_REL, __HIP_MEMORY_SCOPE_AGENT);
    __syncthreads();
    if (old_s == (unsigned)(NB_K2 - 1)) {
        float v;
        v = (tid < NB_RG2P) ? redp[RO_G2P + tid] : 0.f;
        float sGT2P = block_sum256(v, red4);
        v = (tid < NB_RP2) ? redp[RO_P2 + tid] : 0.f;
        float sP2GT = block_sum256(v, red4);
        float a[18];
        #pragma unroll
        for (int k = 0; k < 18; ++k) {
            v = (tid < 79) ? f1p[tid * 24 + k] : 0.f;
            a[k] = block_sum256(v, red4);
        }
        if (tid == 0) {
            const float inv20k = 1.f / 20000.f;
            float mE = a[F_E] * inv20k, mG = a[F_G] * inv20k;
            float L_E = (a[F_E2I] - 2.f*mE*a[F_EI] + mE*mE*a[F_I]) * inv20k;
            float L_G = (a[F_G2I] - 2.f*mG*a[F_GI] + mG*mG*a[F_I]) * inv20k;
            float L_sc = L_E + L_G + (a[F_ST] + a[F_F2I]) * inv20k;
            float L_mc = a[F_MC] * (1.f / 10000.f);
            float L_chd = sP2GT * inv20k + sGT2P * (1.f / 65536.f);
            float L_olap = 0.f;
            #pragma unroll
            for (int b = 0; b < B_; ++b) {
                float At = a[F_AB + b] * (1.f / (float)SPP_);
                float d  = fmaxf(0.f, At - A_gt[b]);
                L_olap += d * d;
            }
            L_olap *= (1.f / (float)B_);
            out[0] = L_chd + L_mc + L_sc + L_olap;
        }
    }
}

extern "C" void kernel_launch(void* const* d_in, const int* in_sizes, int n_in,
                              void* d_out, int out_size, void* d_ws, size_t ws_size,
                              hipStream_t stream) {
    const float* pc_gt   = (const float*)d_in[0];   // (8, 8192, 3)
    const float* pc_pred = (const float*)d_in[1];   // (8, 2500, 3)
    const float* fff     = (const float*)d_in[2];   // (8, 2500, 3)
    const float* A_gt    = (const float*)d_in[3];   // (8,)
    float* ws  = (float*)d_ws;                      // ~1.2 MB used
    float* out = (float*)d_out;

    k1_main  <<<NB_K1, 256, 0, stream>>>(pc_gt, pc_pred, fff, ws);
    k2_reduce<<<NB_K2, 256, 0, stream>>>(fff, A_gt, ws, out);
}

// Round 14
// 96.876 us; speedup vs baseline: 1.0569x; 1.0569x over previous
//
#include <hip/hip_runtime.h>

// Problem constants (from reference: B=8, N=8192, M=2500, P=10)
#define B_   8
#define N_   8192
#define M_   2500
#define SPP_ 250
#define EPS_ 1e-20f
#define BIGF 1e30f

// ---- kernel-1 roles (r9-verified shape) ----
// p2gt: 8 z-chunks (1024 gt) x 8 b x 5 mblk (512 preds)  = 320  (64 iters)
// gt2p: 2 z-chunks (1280 pd) x 8 b x 16 mblk (512 gts)   = 256  (80 iters)
#define NB_P2GT 320
#define NB_GT2P 256
#define NB_FFF  79
#define NB_K1   (NB_P2GT + NB_GT2P + NB_FFF)   // 655

// ---- kernel-2 roles (float4-vectorized) ----
#define NB_RG2P 64     // 65536 cols / (256 thr * 4)
#define NB_RP2  20     // 20000 cols / (256 thr * 4) = 19.5 -> 20
#define NB_K2   (NB_RG2P + NB_RP2)             // 84

// ---- ws layout (float indices) ----
#define WS_P2GT 0            // 8 z x 20000 clamped partial minima
#define WS_GT2P 160000       // 2 z x 65536 clamped partial minima
#define WS_F1P  291072       // 79 x 24 fff partials (non-atomic)
#define WS_RED  292968       // k2 partials: 64 g2p + 20 p2
#define WS_CNT  293052       // k2 arrival counter (uint)
#define RO_G2P 0
#define RO_P2  64
// f1p slot order
#define F_E    0
#define F_G    1
#define F_MC   2
#define F_ST   3
#define F_F2I  4
#define F_E2I  5
#define F_EI   6
#define F_G2I  7
#define F_GI   8
#define F_I    9
#define F_AB   10   // 10..17 per-batch sum sqrt(A2)

typedef __attribute__((ext_vector_type(8))) short short8_t;
typedef __attribute__((ext_vector_type(4))) float float4_t;

__device__ __forceinline__ unsigned pack_bf2(float lo, float hi) {
    unsigned a = __float_as_uint(lo);
    unsigned b = __float_as_uint(hi);
    a = (a + 0x7FFFu + ((a >> 16) & 1u)) >> 16;
    b = (b + 0x7FFFu + ((b >> 16) & 1u)) & 0xFFFF0000u;
    return a | b;
}
__device__ __forceinline__ short bf16s(float x) {
    unsigned a = __float_as_uint(x);
    return (short)((a + 0x7FFFu + ((a >> 16) & 1u)) >> 16);
}
__device__ __forceinline__ float wave_sum64(float v) {
    #pragma unroll
    for (int o = 32; o > 0; o >>= 1) v += __shfl_down(v, o, 64);
    return v;
}
__device__ __forceinline__ float block_sum256(float v, volatile float* red4) {
    v = wave_sum64(v);
    int wid = threadIdx.x >> 6, lane = threadIdx.x & 63;
    if (lane == 0) red4[wid] = v;
    __syncthreads();
    float r = 0.f;
    if (threadIdx.x == 0) r = red4[0] + red4[1] + red4[2] + red4[3];
    __syncthreads();
    return r;
}
__device__ __forceinline__ void min4(float4_t& c, const float4_t d) {
    c.x = fminf(c.x, d.x); c.y = fminf(c.y, d.y);
    c.z = fminf(c.z, d.z); c.w = fminf(c.w, d.w);
}
__device__ __forceinline__ void quad_min4(float4_t& c) {
    #pragma unroll
    for (int m = 1; m < 16; m <<= 1) {
        c.x = fminf(c.x, __shfl_xor(c.x, m, 64));
        c.y = fminf(c.y, __shfl_xor(c.y, m, 64));
        c.z = fminf(c.z, __shfl_xor(c.z, m, 64));
        c.w = fminf(c.w, __shfl_xor(c.w, m, 64));
    }
}

// ============================================================================
// Kernel 1: MFMA chamfer (both directions) + single-pass fff.
// Best-verified structure (r9/r12, 96.8-98.1 us total):
// 16x16x32 bf16 MFMA, K=4 used: A={x,y,z,1}, B={-2bx,-2by,-2bz,|b|^2},
// C = loop-invariant row-norm bias -> D = d^2 directly.
// 8 A-tiles (128 rows)/wave share each ds_read_b128 B-fragment.
// (256,2): ~130 live VGPRs fit without scratch spill (r8 lesson);
// uniform 64/80-iter blocks (r11 lesson: stragglers kill occupancy);
// 8-tile amortization beats 4-tile + more TLP (r10 lesson);
// v_min-per-pair is shape-invariant, so 32x32 MFMA gains nothing (r13).
// ============================================================================
__global__ void __launch_bounds__(256, 2) k1_main(
        const float* __restrict__ gt, const float* __restrict__ pred,
        const float* __restrict__ fff, float* __restrict__ ws) {
    __shared__ uint4 spts[1280];                 // staged B pts, 16 B each
    __shared__ __align__(16) float saux[520];    // 512 row norms + red4
    const int bid = blockIdx.x;
    const int tid = threadIdx.x;
    const int lane = tid & 63;
    const int w    = tid >> 6;
    const int quad = lane >> 4;
    const int l15  = lane & 15;

    if (bid == 0 && tid == 0) ((unsigned*)(ws + WS_CNT))[0] = 0u;

    if (bid < NB_P2GT + NB_GT2P) {
        // ------------------- chamfer role -------------------
        const bool is_p2gt = bid < NB_P2GT;
        int b, mblk, z, ntiles, blim, alim;
        const float* apts; const float* bpts; float* dst;
        if (is_p2gt) {
            z = bid / 40; int rem = bid % 40;
            b = rem / 5;  mblk = rem % 5;
            apts = pred + (size_t)b * M_ * 3;
            bpts = gt + ((size_t)b * N_ + (size_t)z * 1024) * 3;
            ntiles = 64; blim = 1024; alim = M_;
            dst = ws + WS_P2GT + (size_t)z * 20000 + b * M_;
        } else {
            int r = bid - NB_P2GT;
            z = r >> 7; int rem = r & 127;
            b = rem >> 4; mblk = rem & 15;
            apts = gt + (size_t)b * N_ * 3;
            bpts = pred + ((size_t)b * M_ + (size_t)z * 1280) * 3;
            ntiles = 80; blim = M_ - z * 1280; alim = N_;
            dst = ws + WS_GT2P + (size_t)z * 65536 + b * N_;
        }
        const int abase = mblk * 512;
        const int nstage = ntiles * 16;

        // stage B points (bf16, -2 folded, norm in w; halves duplicated)
        for (int i = tid; i < nstage; i += 256) {
            float x = 0.f, y = 0.f, zc = 0.f, n2 = BIGF;
            if (i < blim) {
                x = bpts[i * 3 + 0]; y = bpts[i * 3 + 1]; zc = bpts[i * 3 + 2];
                n2 = x * x + y * y + zc * zc;
            }
            uint4 q;
            q.x = pack_bf2(-2.f * x, -2.f * y);
            q.y = pack_bf2(-2.f * zc, n2);
            q.z = q.x; q.w = q.y;
            spts[i] = q;
        }

        // A fragments: 8 tiles of 16 rows per wave (128 rows); stash norms
        short8_t af[8];
        #pragma unroll
        for (int t = 0; t < 8; ++t) af[t] = (short8_t){0,0,0,0,0,0,0,0};
        if (lane < 16) {
            #pragma unroll
            for (int t = 0; t < 8; ++t) {
                int m = abase + w * 128 + t * 16 + l15;
                int c = m < alim ? m : alim - 1;
                float x = apts[c*3+0], y = apts[c*3+1], zc = apts[c*3+2];
                af[t][0] = bf16s(x); af[t][1] = bf16s(y); af[t][2] = bf16s(zc);
                af[t][3] = (short)0x3F80;  // 1.0 bf16
                saux[w * 128 + t * 16 + l15] = x*x + y*y + zc*zc;
            }
        }
        __syncthreads();

        const float4_t* bp = (const float4_t*)saux;
        float4_t bias[8], c[8];
        #pragma unroll
        for (int t = 0; t < 8; ++t) {
            bias[t] = bp[w * 32 + t * 4 + quad];
            c[t] = (float4_t){BIGF, BIGF, BIGF, BIGF};
        }

        const uint4* bptr = spts + l15;   // quads duplicate address = broadcast
        #pragma unroll 2
        for (int i = 0; i < ntiles; ++i) {
            short8_t bf = __builtin_bit_cast(short8_t, bptr[i * 16]);
            #pragma unroll
            for (int t = 0; t < 8; ++t) {
                float4_t d = __builtin_amdgcn_mfma_f32_16x16x32_bf16(
                                 af[t], bf, bias[t], 0, 0, 0);
                min4(c[t], d);
            }
        }
        #pragma unroll
        for (int t = 0; t < 8; ++t) {
            quad_min4(c[t]);
            c[t].x = fmaxf(c[t].x, 0.f); c[t].y = fmaxf(c[t].y, 0.f);
            c[t].z = fmaxf(c[t].z, 0.f); c[t].w = fmaxf(c[t].w, 0.f);
        }
        if (l15 == 0) {
            #pragma unroll
            for (int t = 0; t < 8; ++t) {
                int m0 = abase + w * 128 + t * 16 + quad * 4;
                if (m0 < alim)   // alim % 4 == 0 -> no straddle
                    *(float4_t*)(dst + m0) = c[t];
            }
        }
    } else {
        // ------------- fff role (single pass, expanded variance) -------------
        const int kb = bid - NB_P2GT - NB_GT2P;
        const int i  = kb * 256 + tid;
        volatile float* red4 = saux + 512;
        float* sA = saux;   // [0..7]
        if (tid < B_) sA[tid] = 0.f;
        __syncthreads();

        float vE=0.f,vG=0.f,vMC=0.f,vST=0.f,vF2=0.f,vE2=0.f,vEI=0.f,
              vG2=0.f,vGI=0.f,vI=0.f;
        if (i < B_ * M_) {
            const int b = i / M_;
            const int m = i - b * M_;
            const float* f = fff + (size_t)i * 3;
            float E = f[0], F = f[1], G = f[2];
            float A2  = fmaxf(E * G - F * F, 0.f);
            float inv = 1.f / (A2 + EPS_);
            vE = E; vG = G;
            vST = (E - G) * (E - G) * inv;
            vF2 = F * F * inv;
            vE2 = E * E * inv; vEI = E * inv;
            vG2 = G * G * inv; vGI = G * inv;
            vI  = inv;
            atomicAdd(&sA[b], sqrtf(A2));
            if ((b & 1) == 0) {
                const float* f2 = fff + ((size_t)(b + 1) * M_ + m) * 3;
                float dE = E - f2[0], dF = F - f2[1], dG = G - f2[2];
                vMC = dE * dE + 2.f * dF * dF + dG * dG;
            }
        }
        float* outp = ws + WS_F1P + (size_t)kb * 24;
        float r;
        r = block_sum256(vE,  red4); if (tid==0) outp[F_E]   = r;
        r = block_sum256(vG,  red4); if (tid==0) outp[F_G]   = r;
        r = block_sum256(vMC, red4); if (tid==0) outp[F_MC]  = r;
        r = block_sum256(vST, red4); if (tid==0) outp[F_ST]  = r;
        r = block_sum256(vF2, red4); if (tid==0) outp[F_F2I] = r;
        r = block_sum256(vE2, red4); if (tid==0) outp[F_E2I] = r;
        r = block_sum256(vEI, red4); if (tid==0) outp[F_EI]  = r;
        r = block_sum256(vG2, red4); if (tid==0) outp[F_G2I] = r;
        r = block_sum256(vGI, red4); if (tid==0) outp[F_GI]  = r;
        r = block_sum256(vI,  red4); if (tid==0) outp[F_I]   = r;
        __syncthreads();
        if (tid < B_) outp[F_AB + tid] = sA[tid];
    }
}

// ============================================================================
// Kernel 2: min-over-z (float4-vectorized) + last-block finalize.
// ============================================================================
__global__ void __launch_bounds__(256) k2_reduce(
        const float* __restrict__ fff, const float* __restrict__ A_gt,
        float* __restrict__ ws, float* __restrict__ out) {
    __shared__ float red4[4];
    const int bid = blockIdx.x;
    const int tid = threadIdx.x;
    float* redp = ws + WS_RED;
    const float* f1p = ws + WS_F1P;

    if (bid < NB_RG2P) {
        // gt2p: min over 2 z-chunks, float4
        const int o = bid * 1024 + tid * 4;          // [0,65536)
        const float4_t v0 = *(const float4_t*)(ws + WS_GT2P + o);
        const float4_t v1 = *(const float4_t*)(ws + WS_GT2P + 65536 + o);
        float s = fminf(v0.x, v1.x) + fminf(v0.y, v1.y)
                + fminf(v0.z, v1.z) + fminf(v0.w, v1.w);
        float r = block_sum256(s, red4);
        if (tid == 0) redp[RO_G2P + bid] = r;
    } else {
        // p2gt: min over 8 z-chunks, float4
        const int kb = bid - NB_RG2P;
        const int o = kb * 1024 + tid * 4;           // [0,20480)
        float s = 0.f;
        if (o < 20000) {                              // 20000 % 4 == 0
            const float* src = ws + WS_P2GT + o;
            float4_t m = *(const float4_t*)src;
            #pragma unroll
            for (int zz = 1; zz < 8; ++zz) {
                float4_t v = *(const float4_t*)(src + zz * 20000);
                m.x = fminf(m.x, v.x); m.y = fminf(m.y, v.y);
                m.z = fminf(m.z, v.z); m.w = fminf(m.w, v.w);
            }
            s = m.x + m.y + m.z + m.w;
        }
        float r = block_sum256(s, red4);
        if (tid == 0) redp[RO_P2 + kb] = r;
    }

    // ---- arrival counter; last block finalizes ----
    __syncthreads();
    if (tid == 0) __threadfence();
    __syncthreads();
    __shared__ unsigned old_s;
    if (tid == 0)
        old_s = __hip_atomic_fetch_add((unsigned*)(ws + WS_CNT), 1u,
                                       __ATOMIC_ACQ_REL, __HIP_MEMORY_SCOPE_AGENT);
    __syncthreads();
    if (old_s == (unsigned)(NB_K2 - 1)) {
        float v;
        v = (tid < NB_RG2P) ? redp[RO_G2P + tid] : 0.f;
        float sGT2P = block_sum256(v, red4);
        v = (tid < NB_RP2) ? redp[RO_P2 + tid] : 0.f;
        float sP2GT = block_sum256(v, red4);
        float a[18];
        #pragma unroll
        for (int k = 0; k < 18; ++k) {
            v = (tid < 79) ? f1p[tid * 24 + k] : 0.f;
            a[k] = block_sum256(v, red4);
        }
        if (tid == 0) {
            const float inv20k = 1.f / 20000.f;
            float mE = a[F_E] * inv20k, mG = a[F_G] * inv20k;
            float L_E = (a[F_E2I] - 2.f*mE*a[F_EI] + mE*mE*a[F_I]) * inv20k;
            float L_G = (a[F_G2I] - 2.f*mG*a[F_GI] + mG*mG*a[F_I]) * inv20k;
            float L_sc = L_E + L_G + (a[F_ST] + a[F_F2I]) * inv20k;
            float L_mc = a[F_MC] * (1.f / 10000.f);
            float L_chd = sP2GT * inv20k + sGT2P * (1.f / 65536.f);
            float L_olap = 0.f;
            #pragma unroll
            for (int b = 0; b < B_; ++b) {
                float At = a[F_AB + b] * (1.f / (float)SPP_);
                float d  = fmaxf(0.f, At - A_gt[b]);
                L_olap += d * d;
            }
            L_olap *= (1.f / (float)B_);
            out[0] = L_chd + L_mc + L_sc + L_olap;
        }
    }
}

extern "C" void kernel_launch(void* const* d_in, const int* in_sizes, int n_in,
                              void* d_out, int out_size, void* d_ws, size_t ws_size,
                              hipStream_t stream) {
    const float* pc_gt   = (const float*)d_in[0];   // (8, 8192, 3)
    const float* pc_pred = (const float*)d_in[1];   // (8, 2500, 3)
    const float* fff     = (const float*)d_in[2];   // (8, 2500, 3)
    const float* A_gt    = (const float*)d_in[3];   // (8,)
    float* ws  = (float*)d_ws;                      // ~1.2 MB used
    float* out = (float*)d_out;

    k1_main  <<<NB_K1, 256, 0, stream>>>(pc_gt, pc_pred, fff, ws);
    k2_reduce<<<NB_K2, 256, 0, stream>>>(fff, A_gt, ws, out);
}